// Round 1
// baseline (966.254 us; speedup 1.0000x reference)
//
#include <hip/hip_runtime.h>

#define N_NODES 50000
#define N_EDGES 600000
#define IN_CH 64
#define HID 128
#define N_GRAPHS 64

// ---------------------------------------------------------------------------
// Edge message + scatter: agg[dst] += relu(x[src] + edge_attr @ el_w + el_b)
// tid = e*D + c  → one wave covers one edge (D=64) or half (D=128):
// src/dst/edge_attr are wave-uniform (broadcast loads), x row + atomics coalesced.
// ---------------------------------------------------------------------------
template <int D>
__global__ void edge_kernel(const float* __restrict__ xin,
                            const int* __restrict__ ei,
                            const float* __restrict__ ea,
                            const float* __restrict__ elw,  // [3, D]
                            const float* __restrict__ elb,  // [D]
                            float* __restrict__ agg) {
    int tid = blockIdx.x * blockDim.x + threadIdx.x;
    if (tid >= N_EDGES * D) return;
    int e = tid / D;
    int c = tid % D;
    int src = ei[e];
    int dst = ei[N_EDGES + e];
    float a0 = ea[e * 3 + 0], a1 = ea[e * 3 + 1], a2 = ea[e * 3 + 2];
    float ev = a0 * elw[c] + a1 * elw[D + c] + a2 * elw[2 * D + c] + elb[c];
    float m = xin[src * D + c] + ev;
    m = m > 0.f ? m : 0.f;
    atomicAdd(&agg[dst * D + c], m);
}

// ---------------------------------------------------------------------------
// Fused node MLP: out = [relu]( relu((x+agg) @ wa + ba) @ wb + bb )
// 128 threads/block, NPB nodes per block (weight value reused NPB× per load).
// POOL: scatter-add result into per-graph pool sums instead of storing h.
// ---------------------------------------------------------------------------
template <int K, int NPB, bool POOL>
__global__ void mlp_kernel(const float* __restrict__ xin,
                           const float* __restrict__ agg,
                           const float* __restrict__ wa,  // [K, HID]
                           const float* __restrict__ ba,
                           const float* __restrict__ wb,  // [HID, HID]
                           const float* __restrict__ bb,
                           float* __restrict__ out,       // [N,HID] or pool sums [G,HID]
                           const int* __restrict__ batch) {
    __shared__ float sIn[NPB][K];
    __shared__ float sHid[NPB][HID];
    const int node0 = blockIdx.x * NPB;
    const int t = threadIdx.x;  // 0..127

    if (t < K) {
        #pragma unroll
        for (int i = 0; i < NPB; i++) {
            int node = node0 + i;
            sIn[i][t] = xin[node * K + t] + agg[node * K + t];
        }
    }
    __syncthreads();

    float acc[NPB];
    #pragma unroll
    for (int i = 0; i < NPB; i++) acc[i] = ba[t];
    for (int k = 0; k < K; k++) {
        float w = wa[k * HID + t];
        #pragma unroll
        for (int i = 0; i < NPB; i++) acc[i] += sIn[i][k] * w;
    }
    #pragma unroll
    for (int i = 0; i < NPB; i++) sHid[i][t] = acc[i] > 0.f ? acc[i] : 0.f;
    __syncthreads();

    float acc2[NPB];
    #pragma unroll
    for (int i = 0; i < NPB; i++) acc2[i] = bb[t];
    for (int k = 0; k < HID; k++) {
        float w = wb[k * HID + t];
        #pragma unroll
        for (int i = 0; i < NPB; i++) acc2[i] += sHid[i][k] * w;
    }

    #pragma unroll
    for (int i = 0; i < NPB; i++) {
        int node = node0 + i;
        float v = acc2[i] > 0.f ? acc2[i] : 0.f;  // outer relu (both layers)
        if (POOL) {
            atomicAdd(&out[batch[node] * HID + t], v);
        } else {
            out[node * HID + t] = v;
        }
    }
}

__global__ void count_kernel(const int* __restrict__ batch, float* __restrict__ cnt) {
    int n = blockIdx.x * blockDim.x + threadIdx.x;
    if (n < N_NODES) atomicAdd(&cnt[batch[n]], 1.0f);
}

__global__ void pool_div_kernel(const float* __restrict__ sums,
                                const float* __restrict__ cnt,
                                float* __restrict__ out) {
    int i = blockIdx.x * blockDim.x + threadIdx.x;
    if (i < N_GRAPHS * HID) {
        float c = cnt[i / HID];
        out[i] = sums[i] / (c > 1.0f ? c : 1.0f);
    }
}

extern "C" void kernel_launch(void* const* d_in, const int* in_sizes, int n_in,
                              void* d_out, int out_size, void* d_ws, size_t ws_size,
                              hipStream_t stream) {
    const float* x    = (const float*)d_in[0];
    const int*   ei   = (const int*)d_in[1];
    const float* ea   = (const float*)d_in[2];
    const int*   batch= (const int*)d_in[3];
    const float* el1w = (const float*)d_in[4];
    const float* el1b = (const float*)d_in[5];
    const float* w1a  = (const float*)d_in[6];
    const float* b1a  = (const float*)d_in[7];
    const float* w1b  = (const float*)d_in[8];
    const float* b1b  = (const float*)d_in[9];
    const float* el2w = (const float*)d_in[10];
    const float* el2b = (const float*)d_in[11];
    const float* w2a  = (const float*)d_in[12];
    const float* b2a  = (const float*)d_in[13];
    const float* w2b  = (const float*)d_in[14];
    const float* b2b  = (const float*)d_in[15];
    float* out = (float*)d_out;

    float* agg  = (float*)d_ws;                       // [N, HID] (layer1 uses [N, IN_CH])
    float* h    = agg + (size_t)N_NODES * HID;        // [N, HID]
    float* psum = h + (size_t)N_NODES * HID;          // [G, HID]
    float* pcnt = psum + N_GRAPHS * HID;              // [G]

    // ---- layer 1 ----
    hipMemsetAsync(agg, 0, (size_t)N_NODES * IN_CH * sizeof(float), stream);
    edge_kernel<IN_CH><<<(N_EDGES * IN_CH + 255) / 256, 256, 0, stream>>>(
        x, ei, ea, el1w, el1b, agg);
    mlp_kernel<IN_CH, 8, false><<<N_NODES / 8, 128, 0, stream>>>(
        x, agg, w1a, b1a, w1b, b1b, h, nullptr);

    // ---- layer 2 (pool fused into MLP epilogue) ----
    hipMemsetAsync(agg, 0, (size_t)N_NODES * HID * sizeof(float), stream);
    hipMemsetAsync(psum, 0, (size_t)(N_GRAPHS * HID + N_GRAPHS) * sizeof(float), stream);
    edge_kernel<HID><<<(N_EDGES * HID + 255) / 256, 256, 0, stream>>>(
        h, ei, ea, el2w, el2b, agg);
    count_kernel<<<(N_NODES + 255) / 256, 256, 0, stream>>>(batch, pcnt);
    mlp_kernel<HID, 8, true><<<N_NODES / 8, 128, 0, stream>>>(
        h, agg, w2a, b2a, w2b, b2b, psum, batch);

    // ---- mean ----
    pool_div_kernel<<<(N_GRAPHS * HID + 255) / 256, 256, 0, stream>>>(psum, pcnt, out);
}

// Round 2
// 657.331 us; speedup vs baseline: 1.4700x; 1.4700x over previous
//
#include <hip/hip_runtime.h>

#define N_NODES 50000
#define N_EDGES 600000
#define IN_CH 64
#define HID 128
#define N_GRAPHS 64

// ---------------------------------------------------------------------------
// Edge message + scatter: agg[dst] += relu(x[src] + edge_attr @ el_w + el_b)
// tid = e*D + c  → one wave covers one edge (D=64) or half (D=128):
// src/dst/edge_attr are wave-uniform (broadcast loads), x row + atomics coalesced.
// ---------------------------------------------------------------------------
template <int D>
__global__ void edge_kernel(const float* __restrict__ xin,
                            const int* __restrict__ ei,
                            const float* __restrict__ ea,
                            const float* __restrict__ elw,  // [3, D]
                            const float* __restrict__ elb,  // [D]
                            float* __restrict__ agg) {
    int tid = blockIdx.x * blockDim.x + threadIdx.x;
    if (tid >= N_EDGES * D) return;
    int e = tid / D;
    int c = tid % D;
    int src = ei[e];
    int dst = ei[N_EDGES + e];
    float a0 = ea[e * 3 + 0], a1 = ea[e * 3 + 1], a2 = ea[e * 3 + 2];
    float ev = a0 * elw[c] + a1 * elw[D + c] + a2 * elw[2 * D + c] + elb[c];
    float m = xin[src * D + c] + ev;
    m = m > 0.f ? m : 0.f;
    atomicAdd(&agg[dst * D + c], m);
}

// ---------------------------------------------------------------------------
// Fused node MLP: out = [relu]( relu((x+agg) @ wa + ba) @ wb + bb )
// 128 threads/block, NPB nodes per block (weight value reused NPB× per load).
// POOL: scatter-add result into per-graph pool sums instead of storing h.
// ---------------------------------------------------------------------------
template <int K, int NPB, bool POOL>
__global__ void mlp_kernel(const float* __restrict__ xin,
                           const float* __restrict__ agg,
                           const float* __restrict__ wa,  // [K, HID]
                           const float* __restrict__ ba,
                           const float* __restrict__ wb,  // [HID, HID]
                           const float* __restrict__ bb,
                           float* __restrict__ out,       // [N,HID] or pool sums [G,HID]
                           const int* __restrict__ batch) {
    __shared__ float sIn[NPB][K];
    __shared__ float sHid[NPB][HID];
    const int node0 = blockIdx.x * NPB;
    const int t = threadIdx.x;  // 0..127

    if (t < K) {
        #pragma unroll
        for (int i = 0; i < NPB; i++) {
            int node = node0 + i;
            sIn[i][t] = xin[node * K + t] + agg[node * K + t];
        }
    }
    __syncthreads();

    float acc[NPB];
    #pragma unroll
    for (int i = 0; i < NPB; i++) acc[i] = ba[t];
    for (int k = 0; k < K; k++) {
        float w = wa[k * HID + t];
        #pragma unroll
        for (int i = 0; i < NPB; i++) acc[i] += sIn[i][k] * w;
    }
    #pragma unroll
    for (int i = 0; i < NPB; i++) sHid[i][t] = acc[i] > 0.f ? acc[i] : 0.f;
    __syncthreads();

    float acc2[NPB];
    #pragma unroll
    for (int i = 0; i < NPB; i++) acc2[i] = bb[t];
    for (int k = 0; k < HID; k++) {
        float w = wb[k * HID + t];
        #pragma unroll
        for (int i = 0; i < NPB; i++) acc2[i] += sHid[i][k] * w;
    }

    #pragma unroll
    for (int i = 0; i < NPB; i++) {
        int node = node0 + i;
        float v = acc2[i] > 0.f ? acc2[i] : 0.f;  // outer relu (both layers)
        if (POOL) {
            atomicAdd(&out[batch[node] * HID + t], v);
        } else {
            out[node * HID + t] = v;
        }
    }
}

// ---------------------------------------------------------------------------
// Pool mean: batch is SORTED, so count[g] = upper_bound(g) - lower_bound(g).
// thread i = g*HID + t; all lanes of a wave share g -> wave-uniform binary
// search, broadcast loads. Replaces the 300us atomic count_kernel (R1 profile:
// 64-way same-address atomic serialization).
// ---------------------------------------------------------------------------
__global__ void pool_div_kernel(const float* __restrict__ sums,
                                const int* __restrict__ batch,
                                float* __restrict__ out) {
    int i = blockIdx.x * blockDim.x + threadIdx.x;
    if (i >= N_GRAPHS * HID) return;
    int g = i / HID;
    // lower bound
    int lo = 0, hi = N_NODES;
    while (lo < hi) { int mid = (lo + hi) >> 1; if (batch[mid] < g) lo = mid + 1; else hi = mid; }
    int start = lo;
    // upper bound
    lo = 0; hi = N_NODES;
    while (lo < hi) { int mid = (lo + hi) >> 1; if (batch[mid] <= g) lo = mid + 1; else hi = mid; }
    float c = (float)(lo - start);
    out[i] = sums[i] / (c > 1.0f ? c : 1.0f);
}

extern "C" void kernel_launch(void* const* d_in, const int* in_sizes, int n_in,
                              void* d_out, int out_size, void* d_ws, size_t ws_size,
                              hipStream_t stream) {
    const float* x    = (const float*)d_in[0];
    const int*   ei   = (const int*)d_in[1];
    const float* ea   = (const float*)d_in[2];
    const int*   batch= (const int*)d_in[3];
    const float* el1w = (const float*)d_in[4];
    const float* el1b = (const float*)d_in[5];
    const float* w1a  = (const float*)d_in[6];
    const float* b1a  = (const float*)d_in[7];
    const float* w1b  = (const float*)d_in[8];
    const float* b1b  = (const float*)d_in[9];
    const float* el2w = (const float*)d_in[10];
    const float* el2b = (const float*)d_in[11];
    const float* w2a  = (const float*)d_in[12];
    const float* b2a  = (const float*)d_in[13];
    const float* w2b  = (const float*)d_in[14];
    const float* b2b  = (const float*)d_in[15];
    float* out = (float*)d_out;

    float* agg  = (float*)d_ws;                       // [N, HID] (layer1 uses [N, IN_CH])
    float* h    = agg + (size_t)N_NODES * HID;        // [N, HID]
    float* psum = h + (size_t)N_NODES * HID;          // [G, HID]

    // ---- layer 1 ----
    hipMemsetAsync(agg, 0, (size_t)N_NODES * IN_CH * sizeof(float), stream);
    edge_kernel<IN_CH><<<(N_EDGES * IN_CH + 255) / 256, 256, 0, stream>>>(
        x, ei, ea, el1w, el1b, agg);
    mlp_kernel<IN_CH, 8, false><<<N_NODES / 8, 128, 0, stream>>>(
        x, agg, w1a, b1a, w1b, b1b, h, nullptr);

    // ---- layer 2 (pool fused into MLP epilogue) ----
    hipMemsetAsync(agg, 0, (size_t)N_NODES * HID * sizeof(float), stream);
    hipMemsetAsync(psum, 0, (size_t)(N_GRAPHS * HID) * sizeof(float), stream);
    edge_kernel<HID><<<(N_EDGES * HID + 255) / 256, 256, 0, stream>>>(
        h, ei, ea, el2w, el2b, agg);
    mlp_kernel<HID, 8, true><<<N_NODES / 8, 128, 0, stream>>>(
        h, agg, w2a, b2a, w2b, b2b, psum, batch);

    // ---- mean (count via binary search on sorted batch) ----
    pool_div_kernel<<<(N_GRAPHS * HID + 255) / 256, 256, 0, stream>>>(psum, batch, out);
}

// Round 3
// 583.630 us; speedup vs baseline: 1.6556x; 1.1263x over previous
//
#include <hip/hip_runtime.h>

#define N_NODES 50000
#define N_EDGES 600000
#define IN_CH 64
#define HID 128
#define N_GRAPHS 64

// ===========================================================================
// CSR build: sort edge IDs by dst via counting sort (deg -> scan -> scatter).
// Replaces R2's scatter-atomic edge kernel whose WRITE_SIZE showed full
// per-edge write-through to HBM (300 MB/dispatch).
// ===========================================================================
__global__ void hist_kernel(const int* __restrict__ ei, int* __restrict__ deg) {
    int e = blockIdx.x * blockDim.x + threadIdx.x;
    if (e < N_EDGES) atomicAdd(&deg[ei[N_EDGES + e]], 1);
}

// Single-block exclusive scan over deg[0..N_NODES) -> rowptr & cursor.
__global__ void scan_kernel(const int* __restrict__ deg,
                            int* __restrict__ rowptr,
                            int* __restrict__ cursor) {
    __shared__ int wsum[16];
    __shared__ int carry_s;
    const int t = threadIdx.x;          // 0..1023
    const int lane = t & 63, wid = t >> 6;
    if (t == 0) carry_s = 0;
    __syncthreads();
    for (int base = 0; base < N_NODES; base += 1024) {
        int i = base + t;
        int v = (i < N_NODES) ? deg[i] : 0;
        int s = v;
        #pragma unroll
        for (int off = 1; off < 64; off <<= 1) {
            int n = __shfl_up(s, off);
            if (lane >= off) s += n;
        }
        if (lane == 63) wsum[wid] = s;
        __syncthreads();
        int wprefix = 0;
        for (int w = 0; w < wid; w++) wprefix += wsum[w];
        int excl = carry_s + wprefix + s - v;   // reads carry_s BEFORE update
        if (i < N_NODES) { rowptr[i] = excl; cursor[i] = excl; }
        __syncthreads();
        if (t == 0) {
            int tot = 0;
            for (int w = 0; w < 16; w++) tot += wsum[w];
            carry_s += tot;
        }
        __syncthreads();
    }
    if (t == 0) rowptr[N_NODES] = carry_s;      // == N_EDGES
}

__global__ void scatter_kernel(const int* __restrict__ ei,
                               int* __restrict__ cursor,
                               int* __restrict__ perm) {
    int e = blockIdx.x * blockDim.x + threadIdx.x;
    if (e < N_EDGES) {
        int dst = ei[N_EDGES + e];
        int pos = atomicAdd(&cursor[dst], 1);
        perm[pos] = e;
    }
}

// ===========================================================================
// Fused GINE layer: per node n,
//   sIn = x[n] + sum_{e: dst(e)=n} relu(x[src(e)] + ea[e]@elw + elb)
//   out = relu( relu(sIn@wa+ba) @ wb + bb )        (outer relu both layers)
// Gather-based: no atomics on node features, h written exactly once.
// Block = 128 threads, NPB nodes. For K=64 the two 64-lane halves each own
// one node so the gather rows stay 256B-coalesced.
// POOL: scatter-add result into per-graph pool sums instead of storing h.
// ===========================================================================
template <int K, int NPB, bool POOL>
__global__ void fused_layer(const float* __restrict__ xin,
                            const int* __restrict__ ei,     // src ids at [0,E)
                            const float* __restrict__ ea,
                            const int* __restrict__ rowptr,
                            const int* __restrict__ perm,
                            const float* __restrict__ elw,  // [3, K]
                            const float* __restrict__ elb,  // [K]
                            const float* __restrict__ wa,   // [K, HID]
                            const float* __restrict__ ba,
                            const float* __restrict__ wb,   // [HID, HID]
                            const float* __restrict__ bb,
                            float* __restrict__ out,        // [N,HID] or psum [G,HID]
                            const int* __restrict__ batch) {
    __shared__ float sIn[NPB][K];
    __shared__ float sHid[NPB][HID];
    const int node0 = blockIdx.x * NPB;
    const int t = threadIdx.x;  // 0..127

    // ---- aggregation (gather over CSR) ----
    if (K == 128) {
        const float w0 = elw[t], w1 = elw[K + t], w2 = elw[2 * K + t], eb = elb[t];
        for (int i = 0; i < NPB; i++) {
            int node = node0 + i;
            float acc = xin[(size_t)node * K + t];
            int jb = rowptr[node], je = rowptr[node + 1];
            for (int j = jb; j < je; j++) {
                int e = perm[j];
                int src = ei[e];
                float a0 = ea[3 * e], a1 = ea[3 * e + 1], a2 = ea[3 * e + 2];
                float ev = a0 * w0 + a1 * w1 + a2 * w2 + eb;
                float m = xin[(size_t)src * K + t] + ev;
                acc += m > 0.f ? m : 0.f;
            }
            sIn[i][t] = acc;
        }
    } else {  // K == 64: two nodes in flight (one per 64-lane half)
        const int c = t & 63, half = t >> 6;
        const float w0 = elw[c], w1 = elw[K + c], w2 = elw[2 * K + c], eb = elb[c];
        for (int i = 0; i < NPB; i += 2) {
            int node = node0 + i + half;
            float acc = xin[(size_t)node * K + c];
            int jb = rowptr[node], je = rowptr[node + 1];
            for (int j = jb; j < je; j++) {
                int e = perm[j];
                int src = ei[e];
                float a0 = ea[3 * e], a1 = ea[3 * e + 1], a2 = ea[3 * e + 2];
                float ev = a0 * w0 + a1 * w1 + a2 * w2 + eb;
                float m = xin[(size_t)src * K + c] + ev;
                acc += m > 0.f ? m : 0.f;
            }
            sIn[i + half][c] = acc;
        }
    }
    __syncthreads();

    // ---- MLP layer A: sHid = relu(sIn @ wa + ba) ----
    float acc[NPB];
    #pragma unroll
    for (int i = 0; i < NPB; i++) acc[i] = ba[t];
    for (int k = 0; k < K; k++) {
        float w = wa[k * HID + t];
        #pragma unroll
        for (int i = 0; i < NPB; i++) acc[i] += sIn[i][k] * w;
    }
    #pragma unroll
    for (int i = 0; i < NPB; i++) sHid[i][t] = acc[i] > 0.f ? acc[i] : 0.f;
    __syncthreads();

    // ---- MLP layer B + outer relu ----
    float acc2[NPB];
    #pragma unroll
    for (int i = 0; i < NPB; i++) acc2[i] = bb[t];
    for (int k = 0; k < HID; k++) {
        float w = wb[k * HID + t];
        #pragma unroll
        for (int i = 0; i < NPB; i++) acc2[i] += sHid[i][k] * w;
    }
    #pragma unroll
    for (int i = 0; i < NPB; i++) {
        int node = node0 + i;
        float v = acc2[i] > 0.f ? acc2[i] : 0.f;
        if (POOL) {
            atomicAdd(&out[batch[node] * HID + t], v);
        } else {
            out[(size_t)node * HID + t] = v;
        }
    }
}

// ---------------------------------------------------------------------------
// Pool mean: batch is SORTED -> count[g] by binary search (wave-uniform).
// ---------------------------------------------------------------------------
__global__ void pool_div_kernel(const float* __restrict__ sums,
                                const int* __restrict__ batch,
                                float* __restrict__ out) {
    int i = blockIdx.x * blockDim.x + threadIdx.x;
    if (i >= N_GRAPHS * HID) return;
    int g = i / HID;
    int lo = 0, hi = N_NODES;
    while (lo < hi) { int mid = (lo + hi) >> 1; if (batch[mid] < g) lo = mid + 1; else hi = mid; }
    int start = lo;
    lo = 0; hi = N_NODES;
    while (lo < hi) { int mid = (lo + hi) >> 1; if (batch[mid] <= g) lo = mid + 1; else hi = mid; }
    float c = (float)(lo - start);
    out[i] = sums[i] / (c > 1.0f ? c : 1.0f);
}

extern "C" void kernel_launch(void* const* d_in, const int* in_sizes, int n_in,
                              void* d_out, int out_size, void* d_ws, size_t ws_size,
                              hipStream_t stream) {
    const float* x    = (const float*)d_in[0];
    const int*   ei   = (const int*)d_in[1];
    const float* ea   = (const float*)d_in[2];
    const int*   batch= (const int*)d_in[3];
    const float* el1w = (const float*)d_in[4];
    const float* el1b = (const float*)d_in[5];
    const float* w1a  = (const float*)d_in[6];
    const float* b1a  = (const float*)d_in[7];
    const float* w1b  = (const float*)d_in[8];
    const float* b1b  = (const float*)d_in[9];
    const float* el2w = (const float*)d_in[10];
    const float* el2b = (const float*)d_in[11];
    const float* w2a  = (const float*)d_in[12];
    const float* b2a  = (const float*)d_in[13];
    const float* w2b  = (const float*)d_in[14];
    const float* b2b  = (const float*)d_in[15];
    float* out = (float*)d_out;

    // workspace layout
    int*   deg    = (int*)d_ws;                      // [N] (doubles as scratch)
    int*   cursor = deg + N_NODES;                   // [N]
    int*   rowptr = cursor + N_NODES;                // [N+1]
    int*   perm   = rowptr + (N_NODES + 1);          // [E]
    float* h      = (float*)(perm + N_EDGES);        // [N, HID]
    float* psum   = h + (size_t)N_NODES * HID;       // [G, HID]

    // ---- CSR build (once, shared by both layers) ----
    hipMemsetAsync(deg, 0, N_NODES * sizeof(int), stream);
    hist_kernel<<<(N_EDGES + 255) / 256, 256, 0, stream>>>(ei, deg);
    scan_kernel<<<1, 1024, 0, stream>>>(deg, rowptr, cursor);
    scatter_kernel<<<(N_EDGES + 255) / 256, 256, 0, stream>>>(ei, cursor, perm);

    // ---- layer 1 (gather + MLP fused) ----
    fused_layer<IN_CH, 8, false><<<N_NODES / 8, 128, 0, stream>>>(
        x, ei, ea, rowptr, perm, el1w, el1b, w1a, b1a, w1b, b1b, h, nullptr);

    // ---- layer 2 (gather + MLP + pool fused) ----
    hipMemsetAsync(psum, 0, N_GRAPHS * HID * sizeof(float), stream);
    fused_layer<HID, 8, true><<<N_NODES / 8, 128, 0, stream>>>(
        h, ei, ea, rowptr, perm, el2w, el2b, w2a, b2a, w2b, b2b, psum, batch);

    // ---- mean (count via binary search on sorted batch) ----
    pool_div_kernel<<<(N_GRAPHS * HID + 255) / 256, 256, 0, stream>>>(psum, batch, out);
}

// Round 4
// 489.914 us; speedup vs baseline: 1.9723x; 1.1913x over previous
//
#include <hip/hip_runtime.h>

#define N_NODES 50000
#define N_EDGES 600000
#define IN_CH 64
#define HID 128
#define N_GRAPHS 64

// ===========================================================================
// CSR build: counting-sort edges by dst. scatter packs a permuted per-edge
// record edata[pos] = {src, a0, a1, a2} so the gather loop does ONE 16B
// broadcast load per edge instead of the R3 chain perm[j] -> ei[e] -> ea[e].
// ===========================================================================
__global__ void hist_kernel(const int* __restrict__ ei, int* __restrict__ deg) {
    int e = blockIdx.x * blockDim.x + threadIdx.x;
    if (e < N_EDGES) atomicAdd(&deg[ei[N_EDGES + e]], 1);
}

// Single-block exclusive scan over deg[0..N_NODES) -> rowptr & cursor.
__global__ void scan_kernel(const int* __restrict__ deg,
                            int* __restrict__ rowptr,
                            int* __restrict__ cursor) {
    __shared__ int wsum[16];
    __shared__ int carry_s;
    const int t = threadIdx.x;          // 0..1023
    const int lane = t & 63, wid = t >> 6;
    if (t == 0) carry_s = 0;
    __syncthreads();
    for (int base = 0; base < N_NODES; base += 1024) {
        int i = base + t;
        int v = (i < N_NODES) ? deg[i] : 0;
        int s = v;
        #pragma unroll
        for (int off = 1; off < 64; off <<= 1) {
            int n = __shfl_up(s, off);
            if (lane >= off) s += n;
        }
        if (lane == 63) wsum[wid] = s;
        __syncthreads();
        int wprefix = 0;
        for (int w = 0; w < wid; w++) wprefix += wsum[w];
        int excl = carry_s + wprefix + s - v;   // reads carry_s BEFORE update
        if (i < N_NODES) { rowptr[i] = excl; cursor[i] = excl; }
        __syncthreads();
        if (t == 0) {
            int tot = 0;
            for (int w = 0; w < 16; w++) tot += wsum[w];
            carry_s += tot;
        }
        __syncthreads();
    }
    if (t == 0) rowptr[N_NODES] = carry_s;      // == N_EDGES
}

__global__ void scatter_kernel(const int* __restrict__ ei,
                               const float* __restrict__ ea,
                               int* __restrict__ cursor,
                               int4* __restrict__ edata) {
    int e = blockIdx.x * blockDim.x + threadIdx.x;
    if (e < N_EDGES) {
        int dst = ei[N_EDGES + e];
        int pos = atomicAdd(&cursor[dst], 1);
        edata[pos] = make_int4(ei[e],
                               __float_as_int(ea[3 * e]),
                               __float_as_int(ea[3 * e + 1]),
                               __float_as_int(ea[3 * e + 2]));
    }
}

// ===========================================================================
// Fused GINE layer: per node n,
//   sIn = x[n] + sum_{e: dst(e)=n} relu(x[src(e)] + ea[e]@elw + elb)
//   out = relu( relu(sIn@wa+ba) @ wb + bb )
// Edge loop unrolled x4: 4 edge records then 4 independent row gathers in
// flight (R3 was 1 chained gather/wave -> VALUBusy 31%, latency-bound).
// ===========================================================================
template <int K, int NPB, bool POOL>
__global__ void fused_layer(const float* __restrict__ xin,
                            const int4* __restrict__ edata,
                            const int* __restrict__ rowptr,
                            const float* __restrict__ elw,  // [3, K]
                            const float* __restrict__ elb,  // [K]
                            const float* __restrict__ wa,   // [K, HID]
                            const float* __restrict__ ba,
                            const float* __restrict__ wb,   // [HID, HID]
                            const float* __restrict__ bb,
                            float* __restrict__ out,        // [N,HID] or psum [G,HID]
                            const int* __restrict__ batch) {
    __shared__ float sIn[NPB][K];
    __shared__ float sHid[NPB][HID];
    const int node0 = blockIdx.x * NPB;
    const int t = threadIdx.x;  // 0..127

    // ---- aggregation (gather over CSR, 4 rows in flight) ----
    {
        const int c = (K == 128) ? t : (t & 63);
        const int half = (K == 128) ? 0 : (t >> 6);
        const int istep = (K == 128) ? 1 : 2;
        const float w0 = elw[c], w1 = elw[K + c], w2 = elw[2 * K + c], eb = elb[c];

        auto term = [&](int4 e, float row) -> float {
            float ev = __int_as_float(e.y) * w0 + __int_as_float(e.z) * w1 +
                       __int_as_float(e.w) * w2 + eb;
            float m = row + ev;
            return m > 0.f ? m : 0.f;
        };

        for (int i = 0; i < NPB; i += istep) {
            int node = node0 + i + half;
            float acc = xin[(size_t)node * K + c];
            int jb = rowptr[node], je = rowptr[node + 1];
            int j = jb;
            for (; j + 4 <= je; j += 4) {
                int4 e0 = edata[j], e1 = edata[j + 1], e2 = edata[j + 2], e3 = edata[j + 3];
                float r0 = xin[(size_t)e0.x * K + c];
                float r1 = xin[(size_t)e1.x * K + c];
                float r2 = xin[(size_t)e2.x * K + c];
                float r3 = xin[(size_t)e3.x * K + c];
                acc += term(e0, r0) + term(e1, r1) + term(e2, r2) + term(e3, r3);
            }
            for (; j < je; j++) {
                int4 e0 = edata[j];
                acc += term(e0, xin[(size_t)e0.x * K + c]);
            }
            sIn[i + half][c] = acc;
        }
    }
    __syncthreads();

    // ---- MLP layer A: sHid = relu(sIn @ wa + ba) ----
    float acc[NPB];
    #pragma unroll
    for (int i = 0; i < NPB; i++) acc[i] = ba[t];
    for (int k = 0; k < K; k++) {
        float w = wa[k * HID + t];
        #pragma unroll
        for (int i = 0; i < NPB; i++) acc[i] += sIn[i][k] * w;
    }
    #pragma unroll
    for (int i = 0; i < NPB; i++) sHid[i][t] = acc[i] > 0.f ? acc[i] : 0.f;
    __syncthreads();

    // ---- MLP layer B + outer relu ----
    float acc2[NPB];
    #pragma unroll
    for (int i = 0; i < NPB; i++) acc2[i] = bb[t];
    for (int k = 0; k < HID; k++) {
        float w = wb[k * HID + t];
        #pragma unroll
        for (int i = 0; i < NPB; i++) acc2[i] += sHid[i][k] * w;
    }
    #pragma unroll
    for (int i = 0; i < NPB; i++) {
        int node = node0 + i;
        float v = acc2[i] > 0.f ? acc2[i] : 0.f;
        if (POOL) {
            atomicAdd(&out[batch[node] * HID + t], v);
        } else {
            out[(size_t)node * HID + t] = v;
        }
    }
}

// ---------------------------------------------------------------------------
// Pool mean: batch is SORTED -> count[g] by binary search (wave-uniform).
// ---------------------------------------------------------------------------
__global__ void pool_div_kernel(const float* __restrict__ sums,
                                const int* __restrict__ batch,
                                float* __restrict__ out) {
    int i = blockIdx.x * blockDim.x + threadIdx.x;
    if (i >= N_GRAPHS * HID) return;
    int g = i / HID;
    int lo = 0, hi = N_NODES;
    while (lo < hi) { int mid = (lo + hi) >> 1; if (batch[mid] < g) lo = mid + 1; else hi = mid; }
    int start = lo;
    lo = 0; hi = N_NODES;
    while (lo < hi) { int mid = (lo + hi) >> 1; if (batch[mid] <= g) lo = mid + 1; else hi = mid; }
    float c = (float)(lo - start);
    out[i] = sums[i] / (c > 1.0f ? c : 1.0f);
}

extern "C" void kernel_launch(void* const* d_in, const int* in_sizes, int n_in,
                              void* d_out, int out_size, void* d_ws, size_t ws_size,
                              hipStream_t stream) {
    const float* x    = (const float*)d_in[0];
    const int*   ei   = (const int*)d_in[1];
    const float* ea   = (const float*)d_in[2];
    const int*   batch= (const int*)d_in[3];
    const float* el1w = (const float*)d_in[4];
    const float* el1b = (const float*)d_in[5];
    const float* w1a  = (const float*)d_in[6];
    const float* b1a  = (const float*)d_in[7];
    const float* w1b  = (const float*)d_in[8];
    const float* b1b  = (const float*)d_in[9];
    const float* el2w = (const float*)d_in[10];
    const float* el2b = (const float*)d_in[11];
    const float* w2a  = (const float*)d_in[12];
    const float* b2a  = (const float*)d_in[13];
    const float* w2b  = (const float*)d_in[14];
    const float* b2b  = (const float*)d_in[15];
    float* out = (float*)d_out;

    // workspace layout (edata first: 16B alignment)
    int4*  edata  = (int4*)d_ws;                     // [E] packed {src,a0,a1,a2}
    int*   deg    = (int*)(edata + N_EDGES);         // [N]
    int*   cursor = deg + N_NODES;                   // [N]
    int*   rowptr = cursor + N_NODES;                // [N+1]
    float* h      = (float*)(rowptr + N_NODES + 2);  // [N, HID] (+1 pad keeps 8B align)
    float* psum   = h + (size_t)N_NODES * HID;       // [G, HID]

    // ---- CSR build (once, shared by both layers) ----
    hipMemsetAsync(deg, 0, N_NODES * sizeof(int), stream);
    hist_kernel<<<(N_EDGES + 255) / 256, 256, 0, stream>>>(ei, deg);
    scan_kernel<<<1, 1024, 0, stream>>>(deg, rowptr, cursor);
    scatter_kernel<<<(N_EDGES + 255) / 256, 256, 0, stream>>>(ei, ea, cursor, edata);

    // ---- layer 1 (gather + MLP fused) ----
    fused_layer<IN_CH, 8, false><<<N_NODES / 8, 128, 0, stream>>>(
        x, edata, rowptr, el1w, el1b, w1a, b1a, w1b, b1b, h, nullptr);

    // ---- layer 2 (gather + MLP + pool fused) ----
    hipMemsetAsync(psum, 0, N_GRAPHS * HID * sizeof(float), stream);
    fused_layer<HID, 8, true><<<N_NODES / 8, 128, 0, stream>>>(
        h, edata, rowptr, el2w, el2b, w2a, b2a, w2b, b2b, psum, batch);

    // ---- mean (count via binary search on sorted batch) ----
    pool_div_kernel<<<(N_GRAPHS * HID + 255) / 256, 256, 0, stream>>>(psum, batch, out);
}